// Round 9
// baseline (615.980 us; speedup 1.0000x reference)
//
#include <hip/hip_runtime.h>

typedef unsigned short u16;
typedef _Float16 f16;
typedef __attribute__((ext_vector_type(8))) _Float16 half8;   // 8 f16 = 4 VGPR
typedef __attribute__((ext_vector_type(8))) short short8;     // raw 16B
typedef __attribute__((ext_vector_type(4))) float f32x4;
typedef __attribute__((ext_vector_type(4))) float f4;
typedef __attribute__((ext_vector_type(4))) u16 u16x4;

#define B_ 16
#define S_ 1024
#define DIN_ 1024
#define H_ 16
#define E_ 128

// log2(e) / (E * 0.5): folded into q at the QKV-projection epilogue so the
// attention softmax is exp2(s) with no per-element multiply.
#define EXPK 0.0225546041776533f

__device__ __forceinline__ u16 f2h(float f) {
  f16 h = (f16)f;                         // v_cvt_f16_f32 (RNE)
  return __builtin_bit_cast(u16, h);
}

__device__ __forceinline__ void gl2lds16(const u16* g, u16* l) {
  // async global->LDS, 16B/lane; LDS dest = wave-uniform base + lane*16
  __builtin_amdgcn_global_load_lds((const __attribute__((address_space(1))) void*)g,
                                   (__attribute__((address_space(3))) void*)l, 16, 0, 0);
}

// ---------------- zero-init fp32 (d_out is poisoned 0xAA) ----------------
__global__ __launch_bounds__(256) void zero_f32(float* __restrict__ p) {
  int i = (blockIdx.x * 256 + threadIdx.x) * 4;
  f4 z = {0.f, 0.f, 0.f, 0.f};
  *reinterpret_cast<f4*>(p + i) = z;
}

// ---------------- elementwise fp32 -> fp16 ----------------
__global__ __launch_bounds__(256) void cvt_f32_f16(const float* __restrict__ in,
                                                   u16* __restrict__ out) {
  int i = (blockIdx.x * 256 + threadIdx.x) * 4;
  f4 v = *reinterpret_cast<const f4*>(in + i);
  u16x4 o;
  o[0] = f2h(v[0]); o[1] = f2h(v[1]); o[2] = f2h(v[2]); o[3] = f2h(v[3]);
  *reinterpret_cast<u16x4*>(out + i) = o;
}

// ---------------- batched [R][C] fp32 -> [C][R] fp16 transpose ----------------
__global__ __launch_bounds__(256) void transpose_cvt(const float* __restrict__ in,
                                                     u16* __restrict__ out,
                                                     int R, int C) {
  __shared__ float tile[32][33];
  const size_t moff = (size_t)blockIdx.z * R * C;
  const float* src = in + moff;
  u16* dst = out + moff;
  int c0 = blockIdx.x * 32, r0 = blockIdx.y * 32;
  int tx = threadIdx.x & 31, ty = threadIdx.x >> 5;  // 32 x 8
#pragma unroll
  for (int i = 0; i < 32; i += 8)
    tile[ty + i][tx] = src[(size_t)(r0 + ty + i) * C + c0 + tx];
  __syncthreads();
#pragma unroll
  for (int i = 0; i < 32; i += 8)
    dst[(size_t)(c0 + ty + i) * R + r0 + tx] = f2h(tile[tx][ty + i]);
}

// ======== 256x256-tile fp16 QKV GEMM, BK=64, A-in-LDS + B-in-registers ======
// 512 threads = 8 waves (2M x 4N), per-wave 128x64 output (acc 8x4 f32x4).
// R8 ledger: with A AND B in LDS the per-CU-per-tile LDS traffic (~256 KB)
// matches the MFMA issue time (~2480cy) -> LDS-BW-bound at 39-44% MfmaUtil
// for EVERY schedule variant. Fix: B (the shared, L2-hot operand) is loaded
// GLOBAL->REGISTERS, one tile ahead, via 8 precomputed lane pointers
// (row = wc*64+nt*16+ln; per-tile offset t*128B folds into the instruction
// offset under full unroll). LDS traffic drops to 160 KB/tile (A write +
// af reads) < MFMA time. Register dataflow correctness is compiler-tracked;
// the only manual sync is the unchanged A-side vmcnt(0)+barrier (R5-R8 x4).
// LDS: 2 x 32 KB A dbuf (chunk-swizzled c^=row&7) + epilogue transpose reuse.
// Epilogue per wave-slab (slab = nt0*2 + (wc>>1) = h*3+c):
//   c<2 : scalar scatter to q (scaled EXPK) / k
//   c==2: vT via LDS transpose (reuse smem), key perm within 32:
//         ptok = (tok&~31)|((tok&12)<<1)|((tok&16)>>2)|(tok&3)  [= R4's perm]
template<int K>
__global__ __launch_bounds__(512, 2) void gemm256_qkv(const u16* __restrict__ A,
                                                      const u16* __restrict__ BT,
                                                      u16* __restrict__ q, u16* __restrict__ kk,
                                                      u16* __restrict__ vT) {
  constexpr int KT = K / 64;
  const int tid = threadIdx.x;
  const int m0 = blockIdx.x * 256;
  const int nt0 = blockIdx.y;                       // N-tile 0..23 (2 slabs of 128)
  const u16* Bblk = BT + (size_t)nt0 * 256 * K;
  __shared__ __align__(16) u16 smem[33536];         // 67,072 B (A dbuf + vT transpose)
  const int w = tid >> 6, lane = tid & 63;
  const int quad = lane >> 4, ln = lane & 15;
  const int wr = w >> 2, wc = w & 3;

  // A staging: issue i (0..3) covers rows i*64..i*64+63; chunk c' = tid&7,
  // global chunk col = c' ^ (row&7); row&7 = (tid>>3)&7 (i*64 = 0 mod 8)
  const int srow = tid >> 3;
  const int scc = (tid & 7) ^ (srow & 7);
  const u16* agp = A + (size_t)(m0 + srow) * K + scc * 8;

#define STAGE_A(buf, t)                                                      \
  do {                                                                       \
    u16* ab_ = smem + (buf) * 16384;                                         \
    _Pragma("unroll") for (int i_ = 0; i_ < 4; i_++)                         \
      gl2lds16(agp + (t) * 64 + (size_t)i_ * 64 * K, ab_ + i_ * 4096 + tid * 8); \
  } while (0)

  // B lane pointers: fragment (nt,k2) = B[wc*64+nt*16+ln][kt*64+k2*32+quad*8 ..+8]
  // (same values the LDS path delivered; per-tile offset t*64 elems = t*128 B imm)
  const u16* bp[4][2];
#pragma unroll
  for (int nt = 0; nt < 4; nt++)
#pragma unroll
    for (int k2 = 0; k2 < 2; k2++)
      bp[nt][k2] = Bblk + (size_t)(wc * 64 + nt * 16 + ln) * K + k2 * 32 + quad * 8;

  // A fragment read offsets (row&7 == ln&7 since 128/64/16 are multiples of 8)
  int offA[8][2];
#pragma unroll
  for (int mt = 0; mt < 8; mt++) {
    int row = wr * 128 + mt * 16 + ln;
#pragma unroll
    for (int k2 = 0; k2 < 2; k2++)
      offA[mt][k2] = row * 64 + (((k2 * 4 + quad) ^ (ln & 7)) * 8);
  }

  f32x4 acc[8][4];
  f32x4 zero = {0.f, 0.f, 0.f, 0.f};
#pragma unroll
  for (int mt = 0; mt < 8; mt++)
#pragma unroll
    for (int nt = 0; nt < 4; nt++) acc[mt][nt] = zero;

  // prologue: A tile 0 -> LDS buf0; B tile 0 -> registers
  STAGE_A(0, 0);
  half8 bcur[2][4];
#pragma unroll
  for (int k2 = 0; k2 < 2; k2++)
#pragma unroll
    for (int nt = 0; nt < 4; nt++)
      bcur[k2][nt] = *reinterpret_cast<const half8*>(bp[nt][k2]);

#pragma unroll
  for (int t = 0; t < KT; t++) {
    asm volatile("s_waitcnt vmcnt(0)" ::: "memory");   // A(t)+B(t) landed (issued 1 iter ago)
    asm volatile("s_barrier" ::: "memory");            // A(t) visible; buf[(t+1)&1] free
    half8 bnxt[2][4];
    if (t < KT - 1) {
      STAGE_A((t + 1) & 1, t + 1);                     // A(t+1) in flight over compute
#pragma unroll
      for (int k2 = 0; k2 < 2; k2++)
#pragma unroll
        for (int nt = 0; nt < 4; nt++)
          bnxt[k2][nt] = *reinterpret_cast<const half8*>(bp[nt][k2] + (t + 1) * 64);
    }
    const u16* ab = smem + (t & 1) * 16384;
#pragma unroll
    for (int k2 = 0; k2 < 2; k2++) {
#pragma unroll
      for (int mh = 0; mh < 2; mh++) {
        half8 af[4];
#pragma unroll
        for (int i = 0; i < 4; i++)
          af[i] = *reinterpret_cast<const half8*>(&ab[offA[mh * 4 + i][k2]]);
        __builtin_amdgcn_s_setprio(1);
#pragma unroll
        for (int i = 0; i < 4; i++)
#pragma unroll
          for (int j = 0; j < 4; j++)
            acc[mh * 4 + i][j] = __builtin_amdgcn_mfma_f32_16x16x32_f16(
                af[i], bcur[k2][j], acc[mh * 4 + i][j], 0, 0, 0);
        __builtin_amdgcn_s_setprio(0);
      }
    }
    if (t < KT - 1) {
#pragma unroll
      for (int k2 = 0; k2 < 2; k2++)
#pragma unroll
        for (int nt = 0; nt < 4; nt++)
          bcur[k2][nt] = bnxt[k2][nt];   // full unroll -> register renaming, no movs
    }
  }
#undef STAGE_A

  // ---------------- epilogue ----------------
  __syncthreads();   // all compute done; smem reusable as transpose buffer
  const int slab = nt0 * 2 + (wc >> 1);   // 0..47 = h*3+c
  const int h = slab / 3, c = slab % 3;
  if (c < 2) {
    u16* dst = (c == 0) ? q : kk;
    const float sc = (c == 0) ? EXPK : 1.0f;
#pragma unroll
    for (int mt = 0; mt < 8; mt++)
#pragma unroll
      for (int nt = 0; nt < 4; nt++)
#pragma unroll
        for (int r = 0; r < 4; r++) {
          int tok = m0 + wr * 128 + mt * 16 + quad * 4 + r;   // C/D row = quad*4+reg
          int bb = tok >> 10, s = tok & 1023;
          int e = (wc & 1) * 64 + nt * 16 + ln;               // C/D col = lane&15
          dst[(((size_t)bb * H_ + h) * S_ + s) * E_ + e] = f2h(acc[mt][nt][r] * sc);
        }
  } else {
    // vT slab: write [e][ptok] into smem (stride 260), packed u16x4 over r
#pragma unroll
    for (int mt = 0; mt < 8; mt++)
#pragma unroll
      for (int nt = 0; nt < 4; nt++) {
        int tok0 = wr * 128 + mt * 16 + quad * 4;   // local row, r=0
        int ptok0 = (tok0 & ~31) | ((tok0 & 12) << 1) | ((tok0 & 16) >> 2);
        int e = (wc & 1) * 64 + nt * 16 + ln;
        u16x4 pp;
#pragma unroll
        for (int r = 0; r < 4; r++) pp[r] = f2h(acc[mt][nt][r]);
        *reinterpret_cast<u16x4*>(&smem[e * 260 + ptok0]) = pp;
      }
  }
  __syncthreads();
  // coalesced vT store (block-uniform: at most one v-slab per 256-N-tile)
  int vslab = -1;
  if ((nt0 * 2) % 3 == 2) vslab = 0;
  else if ((nt0 * 2 + 1) % 3 == 2) vslab = 1;
  if (vslab >= 0) {
    const int hv = (nt0 * 2 + vslab) / 3;
    const int bb = m0 >> 10, sbase = m0 & 1023;
    u16* vbase = vT + (((size_t)bb * H_ + hv) * E_) * S_;
#pragma unroll
    for (int i = 0; i < 8; i++) {
      int e = (tid >> 5) + i * 16, s0 = (tid & 31) * 8;
      *reinterpret_cast<short8*>(&vbase[(size_t)e * S_ + sbase + s0]) =
          *reinterpret_cast<const short8*>(&smem[e * 260 + s0]);
    }
  }
}

// ---------------- 128x128-tile fp16 GEMM, BK=64, B transposed (BT[n][k]) -----
// (used only for the output projection: split-K atomicAdd)
template<int MODE, int KSPLIT, int K>
__global__ __launch_bounds__(256) void gemm_bt(const u16* __restrict__ A,
                                               const u16* __restrict__ BT,
                                               u16* __restrict__ q, u16* __restrict__ kk,
                                               u16* __restrict__ vT, float* __restrict__ out) {
  const int tid = threadIdx.x;
  const int m0 = blockIdx.x * 128;
  const u16* Bblk = BT + (size_t)blockIdx.y * 128 * K;
  __shared__ __align__(16) u16 smem[132 * 128];   // 33,792 B
  u16* As = smem;            // [128][64] chunk-swizzled, 8192 u16
  u16* Bs = smem + 8192;
  const int w = tid >> 6, lane = tid & 63;
  const int quad = lane >> 4, ln = lane & 15;
  const int wr = w >> 1, wc = w & 1;

  const int kbeg = (KSPLIT > 1) ? blockIdx.z * (K / KSPLIT) : 0;
  constexpr int KLEN = K / KSPLIT;

  const int rr = lane >> 3;
  const int cc = (lane & 7) ^ rr;
  const u16* agp[4];
  const u16* bgp[4];
#pragma unroll
  for (int i = 0; i < 4; i++) {
    int row = i * 32 + w * 8 + rr;
    agp[i] = A + (size_t)(m0 + row) * K + kbeg + cc * 8;
    bgp[i] = Bblk + (size_t)row * K + kbeg + cc * 8;
  }

  int offA[4][2], offB[4][2];
#pragma unroll
  for (int mt = 0; mt < 4; mt++) {
    int row = wr * 64 + mt * 16 + ln;
#pragma unroll
    for (int k2 = 0; k2 < 2; k2++)
      offA[mt][k2] = row * 64 + (((k2 * 4 + quad) ^ (ln & 7)) * 8);
  }
#pragma unroll
  for (int nt = 0; nt < 4; nt++) {
    int row = wc * 64 + nt * 16 + ln;
#pragma unroll
    for (int k2 = 0; k2 < 2; k2++)
      offB[nt][k2] = row * 64 + (((k2 * 4 + quad) ^ (ln & 7)) * 8);
  }

  f32x4 acc[4][4];
  f32x4 zero = {0.f, 0.f, 0.f, 0.f};
#pragma unroll
  for (int mt = 0; mt < 4; mt++)
#pragma unroll
    for (int nt = 0; nt < 4; nt++) acc[mt][nt] = zero;

#pragma unroll
  for (int k0 = 0; k0 < KLEN; k0 += 64) {
    __syncthreads();
#pragma unroll
    for (int i = 0; i < 4; i++) {
      gl2lds16(agp[i] + k0, As + i * 2048 + w * 512);
      gl2lds16(bgp[i] + k0, Bs + i * 2048 + w * 512);
    }
    __syncthreads();
#pragma unroll
    for (int k2 = 0; k2 < 2; k2++) {
      half8 af[4], bfr[4];
#pragma unroll
      for (int mt = 0; mt < 4; mt++)
        af[mt] = *reinterpret_cast<const half8*>(&As[offA[mt][k2]]);
#pragma unroll
      for (int nt = 0; nt < 4; nt++)
        bfr[nt] = *reinterpret_cast<const half8*>(&Bs[offB[nt][k2]]);
#pragma unroll
      for (int mt = 0; mt < 4; mt++)
#pragma unroll
        for (int nt = 0; nt < 4; nt++)
          acc[mt][nt] = __builtin_amdgcn_mfma_f32_16x16x32_f16(af[mt], bfr[nt], acc[mt][nt], 0, 0, 0);
    }
  }

  {
#pragma unroll
    for (int mt = 0; mt < 4; mt++)
#pragma unroll
      for (int nt = 0; nt < 4; nt++)
#pragma unroll
        for (int r = 0; r < 4; r++) {
          int row = wr * 64 + mt * 16 + quad * 4 + r;
          int e = wc * 64 + nt * 16 + ln;
          if (KSPLIT > 1)
            atomicAdd(&out[(size_t)(m0 + row) * E_ + e], acc[mt][nt][r]);
          else
            out[(size_t)(m0 + row) * E_ + e] = acc[mt][nt][r];
        }
  }
}

// ---------------- flash attention (no online rescale) ----------------
// REVERTED to the R4-R7 single-buffer form (3 clean passes, best totals).
// R8 lesson: K/V double-buffer moved the 32KB DMA LDS-writes into the
// compute window, contending with the LDS-read-heavy compute -> -13us total.
// q pre-scaled by EXPK -> p = exp2(s) directly. SWAPPED QK^T (R4): each lane
// holds P for its own q-row; with V's key axis bit-permuted (baked into vT),
// exp2'd registers pack directly into the PV A-operand -> P never in LDS.
// LDS = 33,792 B; __launch_bounds__(256,3) (R1: (256,4) spills).
struct SmemKV {
  u16 ks[64 * 128];   // K tile [key][e], chunk-swizzled c^=row&7 (16 chunks/row)
  u16 vs[128 * 64];   // V^T tile [e][key-slot], chunk-swizzled c^=row&7 (8 chunks/row)
};
union SmemAttn {
  u16 qs[128 * 132];  // Q tile [128][128] pad->132 (33,792 B = union size)
  SmemKV s;
};

__global__ __launch_bounds__(256, 3) void attn_kernel(const u16* __restrict__ qg,
                                                      const u16* __restrict__ kg,
                                                      const u16* __restrict__ vg,
                                                      u16* __restrict__ og) {
  __shared__ __align__(16) SmemAttn sm;
  const int tid = threadIdx.x;
  const int id = blockIdx.x;
  const int g = id >> 6, qt = (id >> 3) & 7, x = id & 7;
  const int hb = g * 8 + x;
  const int b = hb >> 4, h = hb & 15;
  const int q0 = qt * 128;
  const size_t bh = (size_t)(b * H_ + h);
  const u16* qp = qg + bh * S_ * E_;
  const u16* kp = kg + bh * S_ * E_;
  const u16* vp = vg + bh * E_ * S_;  // [e][key-slot]
  const int w = tid >> 6, lane = tid & 63, quad = lane >> 4, ln = lane & 15;

#pragma unroll
  for (int i = 0; i < 8; i++) {
    int idx = tid + i * 256;
    int row = idx >> 4, col = (idx & 15) * 8;
    *reinterpret_cast<short8*>(&sm.qs[row * 132 + col]) =
        *reinterpret_cast<const short8*>(&qp[(size_t)(q0 + row) * E_ + col]);
  }
  __syncthreads();
  half8 qf[2][4];
#pragma unroll
  for (int mt = 0; mt < 2; mt++)
#pragma unroll
    for (int ks = 0; ks < 4; ks++)
      qf[mt][ks] = *reinterpret_cast<const half8*>(
          &sm.qs[(w * 32 + mt * 16 + ln) * 132 + ks * 32 + quad * 8]);

  const int krow = w * 4 + (lane >> 4);
  const int kc = ((lane & 15) & 8) | (((lane & 15) & 7) ^ (krow & 7));
  const u16* kbase = kp + (size_t)krow * E_ + kc * 8;
  const int vrow = w * 8 + (lane >> 3);
  const int vc = (lane & 7) ^ ((lane >> 3) & 7);
  const u16* vbase = vp + (size_t)vrow * S_ + vc * 8;

  f32x4 zero = {0.f, 0.f, 0.f, 0.f};
  f32x4 oa[2][8];
#pragma unroll
  for (int mt = 0; mt < 2; mt++)
#pragma unroll
    for (int nt = 0; nt < 8; nt++) oa[mt][nt] = zero;
  float lsum[2] = {0.f, 0.f};

  for (int kt = 0; kt < 16; kt++) {
    __syncthreads();
#pragma unroll
    for (int i = 0; i < 4; i++) {
      gl2lds16(kbase + (size_t)kt * 8192 + i * 16 * E_, &sm.s.ks[(i * 256 + w * 64) * 8]);
      gl2lds16(vbase + (size_t)kt * 64 + i * 32 * S_,   &sm.s.vs[(i * 256 + w * 64) * 8]);
    }
    __syncthreads();

    // S^T = K Q^T (swapped operands: C col = q-row -> P is lane-local per row)
    f32x4 sa[2][4];
#pragma unroll
    for (int mt = 0; mt < 2; mt++)
#pragma unroll
      for (int nt = 0; nt < 4; nt++) sa[mt][nt] = zero;
#pragma unroll
    for (int ks = 0; ks < 4; ks++) {
      half8 kf[4];
#pragma unroll
      for (int nt = 0; nt < 4; nt++) {
        int c = ks * 4 + quad;
        int cs = (c & 8) | ((c & 7) ^ (ln & 7));
        kf[nt] = *reinterpret_cast<const half8*>(&sm.s.ks[(nt * 16 + ln) * 128 + cs * 8]);
      }
#pragma unroll
      for (int mt = 0; mt < 2; mt++)
#pragma unroll
        for (int nt = 0; nt < 4; nt++)
          sa[mt][nt] = __builtin_amdgcn_mfma_f32_16x16x32_f16(kf[nt], qf[mt][ks], sa[mt][nt], 0, 0, 0);
    }

    // p = exp2(s) in registers; pack straight into the PV A-operand.
    half8 pfr[2][2];
#pragma unroll
    for (int mt = 0; mt < 2; mt++) {
      float psum = 0.f;
#pragma unroll
      for (int k2 = 0; k2 < 2; k2++) {
        half8 ph;
#pragma unroll
        for (int hhalf = 0; hhalf < 2; hhalf++)
#pragma unroll
          for (int r = 0; r < 4; r++) {
            float p = exp2f(sa[mt][k2 * 2 + hhalf][r]);
            psum += p;
            ph[hhalf * 4 + r] = (f16)p;
          }
        pfr[mt][k2] = ph;
      }
      lsum[mt] += psum;
    }

    // O += P V (P from registers; no LDS, no barrier)
#pragma unroll
    for (int k2 = 0; k2 < 2; k2++) {
#pragma unroll
      for (int nt8 = 0; nt8 < 8; nt8++) {
        int c = k2 * 4 + quad;
        int cs = c ^ (ln & 7);
        half8 vf = *reinterpret_cast<const half8*>(&sm.s.vs[(nt8 * 16 + ln) * 64 + cs * 8]);
#pragma unroll
        for (int mt = 0; mt < 2; mt++)
          oa[mt][nt8] = __builtin_amdgcn_mfma_f32_16x16x32_f16(pfr[mt][k2], vf, oa[mt][nt8], 0, 0, 0);
      }
    }
  }

  // epilogue
#pragma unroll
  for (int mt = 0; mt < 2; mt++) {
    float l = lsum[mt];
    l += __shfl_xor(l, 16);
    l += __shfl_xor(l, 32);
#pragma unroll
    for (int r = 0; r < 4; r++) {
      float lr = __shfl(l, quad * 4 + r);
      float rl = 1.0f / lr;
      int srow = q0 + w * 32 + mt * 16 + quad * 4 + r;
      size_t base = ((size_t)b * S_ + srow) * (H_ * E_) + (size_t)h * E_;
#pragma unroll
      for (int nt8 = 0; nt8 < 8; nt8++)
        og[base + nt8 * 16 + ln] = f2h(oa[mt][nt8][r] * rl);
    }
  }
}

// ---------------- launch ----------------
extern "C" void kernel_launch(void* const* d_in, const int* in_sizes, int n_in,
                              void* d_out, int out_size, void* d_ws, size_t ws_size,
                              hipStream_t stream) {
  const float* x = (const float*)d_in[0];    // [16,1024,1024]
  const float* W = (const float*)d_in[1];    // [16,3,1024,128]
  const float* Wo = (const float*)d_in[2];   // [2048,128]
  float* out = (float*)d_out;                // [16,1024,128] fp32
  char* ws = (char*)d_ws;

  const size_t WBT_BYTES = (size_t)H_ * 3 * DIN_ * E_ * 2;   // 12,582,912
  const size_t WOT_BYTES = (size_t)H_ * E_ * E_ * 2 * 2;     //    524,288
  const size_t FIXED = WBT_BYTES + WOT_BYTES;

  const size_t XB_PER   = (size_t)S_ * DIN_ * 2;
  const size_t QKV_PER  = (size_t)H_ * S_ * E_ * 2;
  const size_t OB_PER   = (size_t)S_ * H_ * E_ * 2;
  const size_t PER_ITEM = XB_PER + 3 * QKV_PER + OB_PER;     // 18,874,368

  int Bc = 1;
  for (int c = 16; c >= 1; c >>= 1) {
    if (FIXED + (size_t)c * PER_ITEM <= ws_size) { Bc = c; break; }
  }

  u16* WbT = (u16*)(ws);
  u16* WoT = (u16*)(ws + WBT_BYTES);
  char* cb = ws + FIXED;
  u16* xb  = (u16*)(cb);
  u16* qb  = (u16*)(cb + (size_t)Bc * XB_PER);
  u16* kb  = (u16*)(cb + (size_t)Bc * (XB_PER + QKV_PER));
  u16* vTb = (u16*)(cb + (size_t)Bc * (XB_PER + 2 * QKV_PER));
  u16* ob  = (u16*)(cb + (size_t)Bc * (XB_PER + 3 * QKV_PER));

  zero_f32<<<out_size / 1024, 256, 0, stream>>>(out);  // split-K outproj accumulates
  transpose_cvt<<<dim3(4, 32, 48), 256, 0, stream>>>(W, WbT, DIN_, E_);
  transpose_cvt<<<dim3(4, 64, 1), 256, 0, stream>>>(Wo, WoT, H_ * E_, E_);

  for (int b0 = 0; b0 < B_; b0 += Bc) {
    const float* xc = x + (size_t)b0 * S_ * DIN_;
    cvt_f32_f16<<<Bc * S_ * DIN_ / 1024, 256, 0, stream>>>(xc, xb);
    gemm256_qkv<DIN_><<<dim3(Bc * 4, 24), 512, 0, stream>>>(xb, WbT, qb, kb, vTb);
    attn_kernel<<<Bc * 128, 256, 0, stream>>>(qb, kb, vTb, ob);
    gemm_bt<1, 4, H_ * E_><<<dim3(Bc * 8, 1, 4), 256, 0, stream>>>(ob, WoT, nullptr, nullptr,
                                                                   nullptr, out + (size_t)b0 * S_ * E_);
  }
}

// Round 10
// 538.919 us; speedup vs baseline: 1.1430x; 1.1430x over previous
//
#include <hip/hip_runtime.h>

typedef unsigned short u16;
typedef _Float16 f16;
typedef __attribute__((ext_vector_type(8))) _Float16 half8;   // 8 f16 = 4 VGPR
typedef __attribute__((ext_vector_type(8))) short short8;     // raw 16B
typedef __attribute__((ext_vector_type(4))) float f32x4;
typedef __attribute__((ext_vector_type(4))) float f4;
typedef __attribute__((ext_vector_type(4))) u16 u16x4;

#define B_ 16
#define S_ 1024
#define DIN_ 1024
#define H_ 16
#define E_ 128

// log2(e) / (E * 0.5): folded into q at the QKV-projection epilogue so the
// attention softmax is exp2(s) with no per-element multiply.
#define EXPK 0.0225546041776533f

__device__ __forceinline__ u16 f2h(float f) {
  f16 h = (f16)f;                         // v_cvt_f16_f32 (RNE)
  return __builtin_bit_cast(u16, h);
}

__device__ __forceinline__ void gl2lds16(const u16* g, u16* l) {
  // async global->LDS, 16B/lane; LDS dest = wave-uniform base + lane*16
  __builtin_amdgcn_global_load_lds((const __attribute__((address_space(1))) void*)g,
                                   (__attribute__((address_space(3))) void*)l, 16, 0, 0);
}

// ---------------- zero-init fp32 (d_out is poisoned 0xAA) ----------------
__global__ __launch_bounds__(256) void zero_f32(float* __restrict__ p) {
  int i = (blockIdx.x * 256 + threadIdx.x) * 4;
  f4 z = {0.f, 0.f, 0.f, 0.f};
  *reinterpret_cast<f4*>(p + i) = z;
}

// ---------------- elementwise fp32 -> fp16 ----------------
__global__ __launch_bounds__(256) void cvt_f32_f16(const float* __restrict__ in,
                                                   u16* __restrict__ out) {
  int i = (blockIdx.x * 256 + threadIdx.x) * 4;
  f4 v = *reinterpret_cast<const f4*>(in + i);
  u16x4 o;
  o[0] = f2h(v[0]); o[1] = f2h(v[1]); o[2] = f2h(v[2]); o[3] = f2h(v[3]);
  *reinterpret_cast<u16x4*>(out + i) = o;
}

// ---------------- batched [R][C] fp32 -> [C][R] fp16 transpose ----------------
__global__ __launch_bounds__(256) void transpose_cvt(const float* __restrict__ in,
                                                     u16* __restrict__ out,
                                                     int R, int C) {
  __shared__ float tile[32][33];
  const size_t moff = (size_t)blockIdx.z * R * C;
  const float* src = in + moff;
  u16* dst = out + moff;
  int c0 = blockIdx.x * 32, r0 = blockIdx.y * 32;
  int tx = threadIdx.x & 31, ty = threadIdx.x >> 5;  // 32 x 8
#pragma unroll
  for (int i = 0; i < 32; i += 8)
    tile[ty + i][tx] = src[(size_t)(r0 + ty + i) * C + c0 + tx];
  __syncthreads();
#pragma unroll
  for (int i = 0; i < 32; i += 8)
    dst[(size_t)(c0 + ty + i) * R + r0 + tx] = f2h(tile[tx][ty + i]);
}

// ======== 256x256-tile fp16 QKV GEMM, BK=64, phase-paced pipeline ========
// 512 threads = 8 waves (2M x 4N), per-wave 128x64 output (acc 8x4 f32x4).
// LDS 128 KiB: 2 bufs x (A[256][64] + B[256][64]) chunk-swizzled c^=row&7.
// Tile top: vmcnt(0) [loads had a full iteration to land] -> s_barrier ->
// issue next tile's 8 global_load_lds into the other buffer.
// Compute split into 4 phases (mh x k2); this R7 form is the session best
// (533.4 us total). Two attempted "improvements" regressed and are reverted:
//  - R8: attn K/V double-buffer moved DMA LDS-writes into the LDS-read-heavy
//    compute window (-13 us).
//  - R9: B streamed global->registers: per-lane fragment gather has lanes
//    2048 B apart -> 64 scattered 16B transactions/instr, vmem-latency-bound
//    (MfmaUtil 44->26, -83 us). Coalescing (G2) beats LDS-traffic arithmetic.
template<int K>
__global__ __launch_bounds__(512, 2) void gemm256_qkv(const u16* __restrict__ A,
                                                      const u16* __restrict__ BT,
                                                      u16* __restrict__ q, u16* __restrict__ kk,
                                                      u16* __restrict__ vT) {
  constexpr int KT = K / 64;
  const int tid = threadIdx.x;
  const int m0 = blockIdx.x * 256;
  const int nt0 = blockIdx.y;                       // N-tile 0..23 (2 slabs of 128)
  const u16* Bblk = BT + (size_t)nt0 * 256 * K;
  __shared__ __align__(16) u16 smem[65536];         // 131,072 B
  const int w = tid >> 6, lane = tid & 63;
  const int quad = lane >> 4, ln = lane & 15;
  const int wr = w >> 2, wc = w & 3;

  // staging: issue i (0..3) covers rows i*64..i*64+63; chunk c' = tid&7,
  // global chunk col = c' ^ (row&7); row&7 = (tid>>3)&7 (i*64 = 0 mod 8)
  const int srow = tid >> 3;
  const int scc = (tid & 7) ^ (srow & 7);
  const u16* agp = A + (size_t)(m0 + srow) * K + scc * 8;
  const u16* bgp = Bblk + (size_t)srow * K + scc * 8;

#define STAGE256(buf, t)                                                     \
  do {                                                                       \
    u16* ab_ = smem + (buf) * 32768;                                         \
    _Pragma("unroll") for (int i_ = 0; i_ < 4; i_++) {                       \
      gl2lds16(agp + (t) * 64 + (size_t)i_ * 64 * K, ab_ + i_ * 4096 + tid * 8);        \
      gl2lds16(bgp + (t) * 64 + (size_t)i_ * 64 * K, ab_ + 16384 + i_ * 4096 + tid * 8);\
    }                                                                        \
  } while (0)

  // fragment read offsets (row&7 == ln&7 since 128/64/16 are multiples of 8)
  int offA[8][2], offB[4][2];
#pragma unroll
  for (int mt = 0; mt < 8; mt++) {
    int row = wr * 128 + mt * 16 + ln;
#pragma unroll
    for (int k2 = 0; k2 < 2; k2++)
      offA[mt][k2] = row * 64 + (((k2 * 4 + quad) ^ (ln & 7)) * 8);
  }
#pragma unroll
  for (int nt = 0; nt < 4; nt++) {
    int row = wc * 64 + nt * 16 + ln;
#pragma unroll
    for (int k2 = 0; k2 < 2; k2++)
      offB[nt][k2] = 16384 + row * 64 + (((k2 * 4 + quad) ^ (ln & 7)) * 8);
  }

  f32x4 acc[8][4];
  f32x4 zero = {0.f, 0.f, 0.f, 0.f};
#pragma unroll
  for (int mt = 0; mt < 8; mt++)
#pragma unroll
    for (int nt = 0; nt < 4; nt++) acc[mt][nt] = zero;

  STAGE256(0, 0);
#pragma unroll
  for (int t = 0; t < KT; t++) {
    asm volatile("s_waitcnt vmcnt(0)" ::: "memory");   // tile t landed (issued 1 iter ago)
    asm volatile("s_barrier" ::: "memory");            // visible to all; buf[(t+1)&1] free
    if (t < KT - 1) STAGE256((t + 1) & 1, t + 1);      // 8 loads in flight over compute
    const u16* ab = smem + (t & 1) * 32768;
#pragma unroll
    for (int k2 = 0; k2 < 2; k2++) {
      half8 bf[4];
#pragma unroll
      for (int j = 0; j < 4; j++)
        bf[j] = *reinterpret_cast<const half8*>(&ab[offB[j][k2]]);
#pragma unroll
      for (int mh = 0; mh < 2; mh++) {
        half8 af[4];
#pragma unroll
        for (int i = 0; i < 4; i++)
          af[i] = *reinterpret_cast<const half8*>(&ab[offA[mh * 4 + i][k2]]);
        asm volatile("s_barrier" ::: "memory");        // all waves' issue-cluster done
        asm volatile("s_waitcnt lgkmcnt(0)" ::: "memory");
        __builtin_amdgcn_sched_barrier(0);             // rule #18: pin MFMA after wait
        __builtin_amdgcn_s_setprio(1);
#pragma unroll
        for (int i = 0; i < 4; i++)
#pragma unroll
          for (int j = 0; j < 4; j++)
            acc[mh * 4 + i][j] = __builtin_amdgcn_mfma_f32_16x16x32_f16(
                af[i], bf[j], acc[mh * 4 + i][j], 0, 0, 0);
        __builtin_amdgcn_s_setprio(0);
        asm volatile("s_barrier" ::: "memory");        // keep phases aligned
      }
    }
  }
#undef STAGE256

  // ---------------- epilogue ----------------
  __syncthreads();   // all compute done; smem reusable as transpose buffer
  const int slab = nt0 * 2 + (wc >> 1);   // 0..47 = h*3+c
  const int h = slab / 3, c = slab % 3;
  if (c < 2) {
    u16* dst = (c == 0) ? q : kk;
    const float sc = (c == 0) ? EXPK : 1.0f;
#pragma unroll
    for (int mt = 0; mt < 8; mt++)
#pragma unroll
      for (int nt = 0; nt < 4; nt++)
#pragma unroll
        for (int r = 0; r < 4; r++) {
          int tok = m0 + wr * 128 + mt * 16 + quad * 4 + r;   // C/D row = quad*4+reg
          int bb = tok >> 10, s = tok & 1023;
          int e = (wc & 1) * 64 + nt * 16 + ln;               // C/D col = lane&15
          dst[(((size_t)bb * H_ + h) * S_ + s) * E_ + e] = f2h(acc[mt][nt][r] * sc);
        }
  } else {
    // vT slab: write [e][ptok] into smem (stride 260), packed u16x4 over r
#pragma unroll
    for (int mt = 0; mt < 8; mt++)
#pragma unroll
      for (int nt = 0; nt < 4; nt++) {
        int tok0 = wr * 128 + mt * 16 + quad * 4;   // local row, r=0
        int ptok0 = (tok0 & ~31) | ((tok0 & 12) << 1) | ((tok0 & 16) >> 2);
        int e = (wc & 1) * 64 + nt * 16 + ln;
        u16x4 pp;
#pragma unroll
        for (int r = 0; r < 4; r++) pp[r] = f2h(acc[mt][nt][r]);
        *reinterpret_cast<u16x4*>(&smem[e * 260 + ptok0]) = pp;
      }
  }
  __syncthreads();
  // coalesced vT store (block-uniform: at most one v-slab per 256-N-tile)
  int vslab = -1;
  if ((nt0 * 2) % 3 == 2) vslab = 0;
  else if ((nt0 * 2 + 1) % 3 == 2) vslab = 1;
  if (vslab >= 0) {
    const int hv = (nt0 * 2 + vslab) / 3;
    const int bb = m0 >> 10, sbase = m0 & 1023;
    u16* vbase = vT + (((size_t)bb * H_ + hv) * E_) * S_;
#pragma unroll
    for (int i = 0; i < 8; i++) {
      int e = (tid >> 5) + i * 16, s0 = (tid & 31) * 8;
      *reinterpret_cast<short8*>(&vbase[(size_t)e * S_ + sbase + s0]) =
          *reinterpret_cast<const short8*>(&smem[e * 260 + s0]);
    }
  }
}

// ---------------- 128x128-tile fp16 GEMM, BK=64, B transposed (BT[n][k]) -----
// (used only for the output projection: split-K atomicAdd)
template<int MODE, int KSPLIT, int K>
__global__ __launch_bounds__(256) void gemm_bt(const u16* __restrict__ A,
                                               const u16* __restrict__ BT,
                                               u16* __restrict__ q, u16* __restrict__ kk,
                                               u16* __restrict__ vT, float* __restrict__ out) {
  const int tid = threadIdx.x;
  const int m0 = blockIdx.x * 128;
  const u16* Bblk = BT + (size_t)blockIdx.y * 128 * K;
  __shared__ __align__(16) u16 smem[132 * 128];   // 33,792 B
  u16* As = smem;            // [128][64] chunk-swizzled, 8192 u16
  u16* Bs = smem + 8192;
  const int w = tid >> 6, lane = tid & 63;
  const int quad = lane >> 4, ln = lane & 15;
  const int wr = w >> 1, wc = w & 1;

  const int kbeg = (KSPLIT > 1) ? blockIdx.z * (K / KSPLIT) : 0;
  constexpr int KLEN = K / KSPLIT;

  const int rr = lane >> 3;
  const int cc = (lane & 7) ^ rr;
  const u16* agp[4];
  const u16* bgp[4];
#pragma unroll
  for (int i = 0; i < 4; i++) {
    int row = i * 32 + w * 8 + rr;
    agp[i] = A + (size_t)(m0 + row) * K + kbeg + cc * 8;
    bgp[i] = Bblk + (size_t)row * K + kbeg + cc * 8;
  }

  int offA[4][2], offB[4][2];
#pragma unroll
  for (int mt = 0; mt < 4; mt++) {
    int row = wr * 64 + mt * 16 + ln;
#pragma unroll
    for (int k2 = 0; k2 < 2; k2++)
      offA[mt][k2] = row * 64 + (((k2 * 4 + quad) ^ (ln & 7)) * 8);
  }
#pragma unroll
  for (int nt = 0; nt < 4; nt++) {
    int row = wc * 64 + nt * 16 + ln;
#pragma unroll
    for (int k2 = 0; k2 < 2; k2++)
      offB[nt][k2] = row * 64 + (((k2 * 4 + quad) ^ (ln & 7)) * 8);
  }

  f32x4 acc[4][4];
  f32x4 zero = {0.f, 0.f, 0.f, 0.f};
#pragma unroll
  for (int mt = 0; mt < 4; mt++)
#pragma unroll
    for (int nt = 0; nt < 4; nt++) acc[mt][nt] = zero;

#pragma unroll
  for (int k0 = 0; k0 < KLEN; k0 += 64) {
    __syncthreads();
#pragma unroll
    for (int i = 0; i < 4; i++) {
      gl2lds16(agp[i] + k0, As + i * 2048 + w * 512);
      gl2lds16(bgp[i] + k0, Bs + i * 2048 + w * 512);
    }
    __syncthreads();
#pragma unroll
    for (int k2 = 0; k2 < 2; k2++) {
      half8 af[4], bfr[4];
#pragma unroll
      for (int mt = 0; mt < 4; mt++)
        af[mt] = *reinterpret_cast<const half8*>(&As[offA[mt][k2]]);
#pragma unroll
      for (int nt = 0; nt < 4; nt++)
        bfr[nt] = *reinterpret_cast<const half8*>(&Bs[offB[nt][k2]]);
#pragma unroll
      for (int mt = 0; mt < 4; mt++)
#pragma unroll
        for (int nt = 0; nt < 4; nt++)
          acc[mt][nt] = __builtin_amdgcn_mfma_f32_16x16x32_f16(af[mt], bfr[nt], acc[mt][nt], 0, 0, 0);
    }
  }

  {
#pragma unroll
    for (int mt = 0; mt < 4; mt++)
#pragma unroll
      for (int nt = 0; nt < 4; nt++)
#pragma unroll
        for (int r = 0; r < 4; r++) {
          int row = wr * 64 + mt * 16 + quad * 4 + r;
          int e = wc * 64 + nt * 16 + ln;
          if (KSPLIT > 1)
            atomicAdd(&out[(size_t)(m0 + row) * E_ + e], acc[mt][nt][r]);
          else
            out[(size_t)(m0 + row) * E_ + e] = acc[mt][nt][r];
        }
  }
}

// ---------------- flash attention (no online rescale) ----------------
// q pre-scaled by EXPK -> p = exp2(s) directly. K/V staged via global_load_lds
// into XOR-swizzled unpadded LDS. R0's proven 2-barrier loop (R3: dbuf at
// 82KB -> 1 block/CU; R8: dbuf at 65KB still loses -- DMA writes contend
// with the LDS-read-heavy compute window).
// SWAPPED QK^T (T12 idea): sa = mfma(kf, qf) computes S^T, so C-layout
// col=lane&15 = q-row -> each lane holds P for ITS OWN q-row, keys
// {nt*16 + quad*4 + r}. With V's key axis permuted within each 32 block
// (baked into vT), the exp2'd registers pack DIRECTLY into the PV A-operand.
// -> P never touches LDS. LDS = 33,792 B; __launch_bounds__(256,3)
// (R1: (256,4) caps regs at 128/wave -> massive scratch spill).
struct SmemKV {
  u16 ks[64 * 128];   // K tile [key][e], chunk-swizzled c^=row&7 (16 chunks/row)
  u16 vs[128 * 64];   // V^T tile [e][key-slot], chunk-swizzled c^=row&7 (8 chunks/row)
};
union SmemAttn {
  u16 qs[128 * 132];  // Q tile [128][128] pad->132 (33,792 B = union size)
  SmemKV s;
};

__global__ __launch_bounds__(256, 3) void attn_kernel(const u16* __restrict__ qg,
                                                      const u16* __restrict__ kg,
                                                      const u16* __restrict__ vg,
                                                      u16* __restrict__ og) {
  __shared__ __align__(16) SmemAttn sm;
  const int tid = threadIdx.x;
  // id = g*64 + qt*8 + x ; hb = g*8 + x ; all qt of one hb share id%8 (XCD)
  const int id = blockIdx.x;
  const int g = id >> 6, qt = (id >> 3) & 7, x = id & 7;
  const int hb = g * 8 + x;
  const int b = hb >> 4, h = hb & 15;
  const int q0 = qt * 128;
  const size_t bh = (size_t)(b * H_ + h);
  const u16* qp = qg + bh * S_ * E_;
  const u16* kp = kg + bh * S_ * E_;
  const u16* vp = vg + bh * E_ * S_;  // [e][key-slot]
  const int w = tid >> 6, lane = tid & 63, quad = lane >> 4, ln = lane & 15;

#pragma unroll
  for (int i = 0; i < 8; i++) {
    int idx = tid + i * 256;
    int row = idx >> 4, col = (idx & 15) * 8;
    *reinterpret_cast<short8*>(&sm.qs[row * 132 + col]) =
        *reinterpret_cast<const short8*>(&qp[(size_t)(q0 + row) * E_ + col]);
  }
  __syncthreads();
  half8 qf[2][4];
#pragma unroll
  for (int mt = 0; mt < 2; mt++)
#pragma unroll
    for (int ks = 0; ks < 4; ks++)
      qf[mt][ks] = *reinterpret_cast<const half8*>(
          &sm.qs[(w * 32 + mt * 16 + ln) * 132 + ks * 32 + quad * 8]);

  const int krow = w * 4 + (lane >> 4);
  const int kc = ((lane & 15) & 8) | (((lane & 15) & 7) ^ (krow & 7));
  const u16* kbase = kp + (size_t)krow * E_ + kc * 8;
  const int vrow = w * 8 + (lane >> 3);
  const int vc = (lane & 7) ^ ((lane >> 3) & 7);
  const u16* vbase = vp + (size_t)vrow * S_ + vc * 8;

  f32x4 zero = {0.f, 0.f, 0.f, 0.f};
  f32x4 oa[2][8];
#pragma unroll
  for (int mt = 0; mt < 2; mt++)
#pragma unroll
    for (int nt = 0; nt < 8; nt++) oa[mt][nt] = zero;
  float lsum[2] = {0.f, 0.f};

  for (int kt = 0; kt < 16; kt++) {
    __syncthreads();
#pragma unroll
    for (int i = 0; i < 4; i++) {
      gl2lds16(kbase + (size_t)kt * 8192 + i * 16 * E_, &sm.s.ks[(i * 256 + w * 64) * 8]);
      gl2lds16(vbase + (size_t)kt * 64 + i * 32 * S_,   &sm.s.vs[(i * 256 + w * 64) * 8]);
    }
    __syncthreads();

    // S^T = K Q^T (swapped operands: C col = q-row -> P is lane-local per row)
    f32x4 sa[2][4];
#pragma unroll
    for (int mt = 0; mt < 2; mt++)
#pragma unroll
      for (int nt = 0; nt < 4; nt++) sa[mt][nt] = zero;
#pragma unroll
    for (int ks = 0; ks < 4; ks++) {
      half8 kf[4];
#pragma unroll
      for (int nt = 0; nt < 4; nt++) {
        int c = ks * 4 + quad;
        int cs = (c & 8) | ((c & 7) ^ (ln & 7));
        kf[nt] = *reinterpret_cast<const half8*>(&sm.s.ks[(nt * 16 + ln) * 128 + cs * 8]);
      }
#pragma unroll
      for (int mt = 0; mt < 2; mt++)
#pragma unroll
        for (int nt = 0; nt < 4; nt++)
          sa[mt][nt] = __builtin_amdgcn_mfma_f32_16x16x32_f16(kf[nt], qf[mt][ks], sa[mt][nt], 0, 0, 0);
    }

    // p = exp2(s) in registers; pack straight into the PV A-operand.
    half8 pfr[2][2];
#pragma unroll
    for (int mt = 0; mt < 2; mt++) {
      float psum = 0.f;
#pragma unroll
      for (int k2 = 0; k2 < 2; k2++) {
        half8 ph;
#pragma unroll
        for (int hhalf = 0; hhalf < 2; hhalf++)
#pragma unroll
          for (int r = 0; r < 4; r++) {
            float p = exp2f(sa[mt][k2 * 2 + hhalf][r]);
            psum += p;
            ph[hhalf * 4 + r] = (f16)p;
          }
        pfr[mt][k2] = ph;
      }
      lsum[mt] += psum;
    }

    // O += P V (P from registers; no LDS, no barrier)
#pragma unroll
    for (int k2 = 0; k2 < 2; k2++) {
#pragma unroll
      for (int nt8 = 0; nt8 < 8; nt8++) {
        int c = k2 * 4 + quad;
        int cs = c ^ (ln & 7);
        half8 vf = *reinterpret_cast<const half8*>(&sm.s.vs[(nt8 * 16 + ln) * 64 + cs * 8]);
#pragma unroll
        for (int mt = 0; mt < 2; mt++)
          oa[mt][nt8] = __builtin_amdgcn_mfma_f32_16x16x32_f16(pfr[mt][k2], vf, oa[mt][nt8], 0, 0, 0);
      }
    }
  }

  // epilogue
#pragma unroll
  for (int mt = 0; mt < 2; mt++) {
    float l = lsum[mt];
    l += __shfl_xor(l, 16);
    l += __shfl_xor(l, 32);
#pragma unroll
    for (int r = 0; r < 4; r++) {
      float lr = __shfl(l, quad * 4 + r);
      float rl = 1.0f / lr;
      int srow = q0 + w * 32 + mt * 16 + quad * 4 + r;
      size_t base = ((size_t)b * S_ + srow) * (H_ * E_) + (size_t)h * E_;
#pragma unroll
      for (int nt8 = 0; nt8 < 8; nt8++)
        og[base + nt8 * 16 + ln] = f2h(oa[mt][nt8][r] * rl);
    }
  }
}

// ---------------- launch ----------------
extern "C" void kernel_launch(void* const* d_in, const int* in_sizes, int n_in,
                              void* d_out, int out_size, void* d_ws, size_t ws_size,
                              hipStream_t stream) {
  const float* x = (const float*)d_in[0];    // [16,1024,1024]
  const float* W = (const float*)d_in[1];    // [16,3,1024,128]
  const float* Wo = (const float*)d_in[2];   // [2048,128]
  float* out = (float*)d_out;                // [16,1024,128] fp32
  char* ws = (char*)d_ws;

  const size_t WBT_BYTES = (size_t)H_ * 3 * DIN_ * E_ * 2;   // 12,582,912
  const size_t WOT_BYTES = (size_t)H_ * E_ * E_ * 2 * 2;     //    524,288
  const size_t FIXED = WBT_BYTES + WOT_BYTES;

  const size_t XB_PER   = (size_t)S_ * DIN_ * 2;
  const size_t QKV_PER  = (size_t)H_ * S_ * E_ * 2;
  const size_t OB_PER   = (size_t)S_ * H_ * E_ * 2;
  const size_t PER_ITEM = XB_PER + 3 * QKV_PER + OB_PER;     // 18,874,368

  int Bc = 1;
  for (int c = 16; c >= 1; c >>= 1) {
    if (FIXED + (size_t)c * PER_ITEM <= ws_size) { Bc = c; break; }
  }

  u16* WbT = (u16*)(ws);
  u16* WoT = (u16*)(ws + WBT_BYTES);
  char* cb = ws + FIXED;
  u16* xb  = (u16*)(cb);
  u16* qb  = (u16*)(cb + (size_t)Bc * XB_PER);
  u16* kb  = (u16*)(cb + (size_t)Bc * (XB_PER + QKV_PER));
  u16* vTb = (u16*)(cb + (size_t)Bc * (XB_PER + 2 * QKV_PER));
  u16* ob  = (u16*)(cb + (size_t)Bc * (XB_PER + 3 * QKV_PER));

  zero_f32<<<out_size / 1024, 256, 0, stream>>>(out);  // split-K outproj accumulates
  transpose_cvt<<<dim3(4, 32, 48), 256, 0, stream>>>(W, WbT, DIN_, E_);
  transpose_cvt<<<dim3(4, 64, 1), 256, 0, stream>>>(Wo, WoT, H_ * E_, E_);

  for (int b0 = 0; b0 < B_; b0 += Bc) {
    const float* xc = x + (size_t)b0 * S_ * DIN_;
    cvt_f32_f16<<<Bc * S_ * DIN_ / 1024, 256, 0, stream>>>(xc, xb);
    gemm256_qkv<DIN_><<<dim3(Bc * 4, 24), 512, 0, stream>>>(xb, WbT, qb, kb, vTb);
    attn_kernel<<<Bc * 128, 256, 0, stream>>>(qb, kb, vTb, ob);
    gemm_bt<1, 4, H_ * E_><<<dim3(Bc * 8, 1, 4), 256, 0, stream>>>(ob, WoT, nullptr, nullptr,
                                                                   nullptr, out + (size_t)b0 * S_ * E_);
  }
}

// Round 12
// 530.258 us; speedup vs baseline: 1.1617x; 1.0163x over previous
//
#include <hip/hip_runtime.h>

typedef unsigned short u16;
typedef _Float16 f16;
typedef __attribute__((ext_vector_type(8))) _Float16 half8;   // 8 f16 = 4 VGPR
typedef __attribute__((ext_vector_type(8))) short short8;     // raw 16B
typedef __attribute__((ext_vector_type(4))) float f32x4;
typedef __attribute__((ext_vector_type(4))) float f4;
typedef __attribute__((ext_vector_type(4))) u16 u16x4;

#define B_ 16
#define S_ 1024
#define DIN_ 1024
#define H_ 16
#define E_ 128

// log2(e) / (E * 0.5): folded into q at the QKV-projection epilogue so the
// attention softmax is exp2(s) with no per-element multiply.
#define EXPK 0.0225546041776533f

__device__ __forceinline__ u16 f2h(float f) {
  f16 h = (f16)f;                         // v_cvt_f16_f32 (RNE)
  return __builtin_bit_cast(u16, h);
}

__device__ __forceinline__ void gl2lds16(const u16* g, u16* l) {
  // async global->LDS, 16B/lane; LDS dest = wave-uniform base + lane*16
  __builtin_amdgcn_global_load_lds((const __attribute__((address_space(1))) void*)g,
                                   (__attribute__((address_space(3))) void*)l, 16, 0, 0);
}

// ---------------- zero-init fp32 (d_out is poisoned 0xAA) ----------------
__global__ __launch_bounds__(256) void zero_f32(float* __restrict__ p) {
  int i = (blockIdx.x * 256 + threadIdx.x) * 4;
  f4 z = {0.f, 0.f, 0.f, 0.f};
  *reinterpret_cast<f4*>(p + i) = z;
}

// ---------------- elementwise fp32 -> fp16 ----------------
__global__ __launch_bounds__(256) void cvt_f32_f16(const float* __restrict__ in,
                                                   u16* __restrict__ out) {
  int i = (blockIdx.x * 256 + threadIdx.x) * 4;
  f4 v = *reinterpret_cast<const f4*>(in + i);
  u16x4 o;
  o[0] = f2h(v[0]); o[1] = f2h(v[1]); o[2] = f2h(v[2]); o[3] = f2h(v[3]);
  *reinterpret_cast<u16x4*>(out + i) = o;
}

// ---------------- batched [R][C] fp32 -> [C][R] fp16 transpose ----------------
__global__ __launch_bounds__(256) void transpose_cvt(const float* __restrict__ in,
                                                     u16* __restrict__ out,
                                                     int R, int C) {
  __shared__ float tile[32][33];
  const size_t moff = (size_t)blockIdx.z * R * C;
  const float* src = in + moff;
  u16* dst = out + moff;
  int c0 = blockIdx.x * 32, r0 = blockIdx.y * 32;
  int tx = threadIdx.x & 31, ty = threadIdx.x >> 5;  // 32 x 8
#pragma unroll
  for (int i = 0; i < 32; i += 8)
    tile[ty + i][tx] = src[(size_t)(r0 + ty + i) * C + c0 + tx];
  __syncthreads();
#pragma unroll
  for (int i = 0; i < 32; i += 8)
    dst[(size_t)(c0 + ty + i) * R + r0 + tx] = f2h(tile[tx][ty + i]);
}

// ======== 256x256-tile fp16 QKV GEMM, BK=64, phase-paced pipeline ========
// 512 threads = 8 waves (2M x 4N), per-wave 128x64 output (acc 8x4 f32x4).
// LDS 128 KiB: 2 bufs x (A[256][64] + B[256][64]) chunk-swizzled c^=row&7.
// Tile top: vmcnt(0) [loads had a full iteration to land] -> s_barrier ->
// issue next tile's 8 global_load_lds into the other buffer.
// Compute split into 4 phases (mh x k2); this R7 form is the session best.
// Reverted attempts: R8 attn dbuf (DMA writes in compute window, -13us);
// R9 B->registers (per-lane gather uncoalesced, lanes 2048B apart, -83us).
template<int K>
__global__ __launch_bounds__(512, 2) void gemm256_qkv(const u16* __restrict__ A,
                                                      const u16* __restrict__ BT,
                                                      u16* __restrict__ q, u16* __restrict__ kk,
                                                      u16* __restrict__ vT) {
  constexpr int KT = K / 64;
  const int tid = threadIdx.x;
  const int m0 = blockIdx.x * 256;
  const int nt0 = blockIdx.y;                       // N-tile 0..23 (2 slabs of 128)
  const u16* Bblk = BT + (size_t)nt0 * 256 * K;
  __shared__ __align__(16) u16 smem[65536];         // 131,072 B
  const int w = tid >> 6, lane = tid & 63;
  const int quad = lane >> 4, ln = lane & 15;
  const int wr = w >> 2, wc = w & 3;

  // staging: issue i (0..3) covers rows i*64..i*64+63; chunk c' = tid&7,
  // global chunk col = c' ^ (row&7); row&7 = (tid>>3)&7 (i*64 = 0 mod 8)
  const int srow = tid >> 3;
  const int scc = (tid & 7) ^ (srow & 7);
  const u16* agp = A + (size_t)(m0 + srow) * K + scc * 8;
  const u16* bgp = Bblk + (size_t)srow * K + scc * 8;

#define STAGE256(buf, t)                                                     \
  do {                                                                       \
    u16* ab_ = smem + (buf) * 32768;                                         \
    _Pragma("unroll") for (int i_ = 0; i_ < 4; i_++) {                       \
      gl2lds16(agp + (t) * 64 + (size_t)i_ * 64 * K, ab_ + i_ * 4096 + tid * 8);        \
      gl2lds16(bgp + (t) * 64 + (size_t)i_ * 64 * K, ab_ + 16384 + i_ * 4096 + tid * 8);\
    }                                                                        \
  } while (0)

  // fragment read offsets (row&7 == ln&7 since 128/64/16 are multiples of 8)
  int offA[8][2], offB[4][2];
#pragma unroll
  for (int mt = 0; mt < 8; mt++) {
    int row = wr * 128 + mt * 16 + ln;
#pragma unroll
    for (int k2 = 0; k2 < 2; k2++)
      offA[mt][k2] = row * 64 + (((k2 * 4 + quad) ^ (ln & 7)) * 8);
  }
#pragma unroll
  for (int nt = 0; nt < 4; nt++) {
    int row = wc * 64 + nt * 16 + ln;
#pragma unroll
    for (int k2 = 0; k2 < 2; k2++)
      offB[nt][k2] = 16384 + row * 64 + (((k2 * 4 + quad) ^ (ln & 7)) * 8);
  }

  f32x4 acc[8][4];
  f32x4 zero = {0.f, 0.f, 0.f, 0.f};
#pragma unroll
  for (int mt = 0; mt < 8; mt++)
#pragma unroll
    for (int nt = 0; nt < 4; nt++) acc[mt][nt] = zero;

  STAGE256(0, 0);
#pragma unroll
  for (int t = 0; t < KT; t++) {
    asm volatile("s_waitcnt vmcnt(0)" ::: "memory");   // tile t landed (issued 1 iter ago)
    asm volatile("s_barrier" ::: "memory");            // visible to all; buf[(t+1)&1] free
    if (t < KT - 1) STAGE256((t + 1) & 1, t + 1);      // 8 loads in flight over compute
    const u16* ab = smem + (t & 1) * 32768;
#pragma unroll
    for (int k2 = 0; k2 < 2; k2++) {
      half8 bf[4];
#pragma unroll
      for (int j = 0; j < 4; j++)
        bf[j] = *reinterpret_cast<const half8*>(&ab[offB[j][k2]]);
#pragma unroll
      for (int mh = 0; mh < 2; mh++) {
        half8 af[4];
#pragma unroll
        for (int i = 0; i < 4; i++)
          af[i] = *reinterpret_cast<const half8*>(&ab[offA[mh * 4 + i][k2]]);
        asm volatile("s_barrier" ::: "memory");        // all waves' issue-cluster done
        asm volatile("s_waitcnt lgkmcnt(0)" ::: "memory");
        __builtin_amdgcn_sched_barrier(0);             // rule #18: pin MFMA after wait
        __builtin_amdgcn_s_setprio(1);
#pragma unroll
        for (int i = 0; i < 4; i++)
#pragma unroll
          for (int j = 0; j < 4; j++)
            acc[mh * 4 + i][j] = __builtin_amdgcn_mfma_f32_16x16x32_f16(
                af[i], bf[j], acc[mh * 4 + i][j], 0, 0, 0);
        __builtin_amdgcn_s_setprio(0);
        asm volatile("s_barrier" ::: "memory");        // keep phases aligned
      }
    }
  }
#undef STAGE256

  // ---------------- epilogue ----------------
  __syncthreads();   // all compute done; smem reusable as transpose buffer
  const int slab = nt0 * 2 + (wc >> 1);   // 0..47 = h*3+c
  const int h = slab / 3, c = slab % 3;
  if (c < 2) {
    u16* dst = (c == 0) ? q : kk;
    const float sc = (c == 0) ? EXPK : 1.0f;
#pragma unroll
    for (int mt = 0; mt < 8; mt++)
#pragma unroll
      for (int nt = 0; nt < 4; nt++)
#pragma unroll
        for (int r = 0; r < 4; r++) {
          int tok = m0 + wr * 128 + mt * 16 + quad * 4 + r;   // C/D row = quad*4+reg
          int bb = tok >> 10, s = tok & 1023;
          int e = (wc & 1) * 64 + nt * 16 + ln;               // C/D col = lane&15
          dst[(((size_t)bb * H_ + h) * S_ + s) * E_ + e] = f2h(acc[mt][nt][r] * sc);
        }
  } else {
    // vT slab: write [e][ptok] into smem (stride 260), packed u16x4 over r
#pragma unroll
    for (int mt = 0; mt < 8; mt++)
#pragma unroll
      for (int nt = 0; nt < 4; nt++) {
        int tok0 = wr * 128 + mt * 16 + quad * 4;   // local row, r=0
        int ptok0 = (tok0 & ~31) | ((tok0 & 12) << 1) | ((tok0 & 16) >> 2);
        int e = (wc & 1) * 64 + nt * 16 + ln;
        u16x4 pp;
#pragma unroll
        for (int r = 0; r < 4; r++) pp[r] = f2h(acc[mt][nt][r]);
        *reinterpret_cast<u16x4*>(&smem[e * 260 + ptok0]) = pp;
      }
  }
  __syncthreads();
  // coalesced vT store (block-uniform: at most one v-slab per 256-N-tile)
  int vslab = -1;
  if ((nt0 * 2) % 3 == 2) vslab = 0;
  else if ((nt0 * 2 + 1) % 3 == 2) vslab = 1;
  if (vslab >= 0) {
    const int hv = (nt0 * 2 + vslab) / 3;
    const int bb = m0 >> 10, sbase = m0 & 1023;
    u16* vbase = vT + (((size_t)bb * H_ + hv) * E_) * S_;
#pragma unroll
    for (int i = 0; i < 8; i++) {
      int e = (tid >> 5) + i * 16, s0 = (tid & 31) * 8;
      *reinterpret_cast<short8*>(&vbase[(size_t)e * S_ + sbase + s0]) =
          *reinterpret_cast<const short8*>(&smem[e * 260 + s0]);
    }
  }
}

// ---------------- 128x128-tile fp16 GEMM, BK=64, B transposed (BT[n][k]) -----
// (used only for the output projection: split-K atomicAdd)
template<int MODE, int KSPLIT, int K>
__global__ __launch_bounds__(256) void gemm_bt(const u16* __restrict__ A,
                                               const u16* __restrict__ BT,
                                               u16* __restrict__ q, u16* __restrict__ kk,
                                               u16* __restrict__ vT, float* __restrict__ out) {
  const int tid = threadIdx.x;
  const int m0 = blockIdx.x * 128;
  const u16* Bblk = BT + (size_t)blockIdx.y * 128 * K;
  __shared__ __align__(16) u16 smem[132 * 128];   // 33,792 B
  u16* As = smem;            // [128][64] chunk-swizzled, 8192 u16
  u16* Bs = smem + 8192;
  const int w = tid >> 6, lane = tid & 63;
  const int quad = lane >> 4, ln = lane & 15;
  const int wr = w >> 1, wc = w & 1;

  const int kbeg = (KSPLIT > 1) ? blockIdx.z * (K / KSPLIT) : 0;
  constexpr int KLEN = K / KSPLIT;

  const int rr = lane >> 3;
  const int cc = (lane & 7) ^ rr;
  const u16* agp[4];
  const u16* bgp[4];
#pragma unroll
  for (int i = 0; i < 4; i++) {
    int row = i * 32 + w * 8 + rr;
    agp[i] = A + (size_t)(m0 + row) * K + kbeg + cc * 8;
    bgp[i] = Bblk + (size_t)row * K + kbeg + cc * 8;
  }

  int offA[4][2], offB[4][2];
#pragma unroll
  for (int mt = 0; mt < 4; mt++) {
    int row = wr * 64 + mt * 16 + ln;
#pragma unroll
    for (int k2 = 0; k2 < 2; k2++)
      offA[mt][k2] = row * 64 + (((k2 * 4 + quad) ^ (ln & 7)) * 8);
  }
#pragma unroll
  for (int nt = 0; nt < 4; nt++) {
    int row = wc * 64 + nt * 16 + ln;
#pragma unroll
    for (int k2 = 0; k2 < 2; k2++)
      offB[nt][k2] = row * 64 + (((k2 * 4 + quad) ^ (ln & 7)) * 8);
  }

  f32x4 acc[4][4];
  f32x4 zero = {0.f, 0.f, 0.f, 0.f};
#pragma unroll
  for (int mt = 0; mt < 4; mt++)
#pragma unroll
    for (int nt = 0; nt < 4; nt++) acc[mt][nt] = zero;

#pragma unroll
  for (int k0 = 0; k0 < KLEN; k0 += 64) {
    __syncthreads();
#pragma unroll
    for (int i = 0; i < 4; i++) {
      gl2lds16(agp[i] + k0, As + i * 2048 + w * 512);
      gl2lds16(bgp[i] + k0, Bs + i * 2048 + w * 512);
    }
    __syncthreads();
#pragma unroll
    for (int k2 = 0; k2 < 2; k2++) {
      half8 af[4], bfr[4];
#pragma unroll
      for (int mt = 0; mt < 4; mt++)
        af[mt] = *reinterpret_cast<const half8*>(&As[offA[mt][k2]]);
#pragma unroll
      for (int nt = 0; nt < 4; nt++)
        bfr[nt] = *reinterpret_cast<const half8*>(&Bs[offB[nt][k2]]);
#pragma unroll
      for (int mt = 0; mt < 4; mt++)
#pragma unroll
        for (int nt = 0; nt < 4; nt++)
          acc[mt][nt] = __builtin_amdgcn_mfma_f32_16x16x32_f16(af[mt], bfr[nt], acc[mt][nt], 0, 0, 0);
    }
  }

  {
#pragma unroll
    for (int mt = 0; mt < 4; mt++)
#pragma unroll
      for (int nt = 0; nt < 4; nt++)
#pragma unroll
        for (int r = 0; r < 4; r++) {
          int row = wr * 64 + mt * 16 + quad * 4 + r;
          int e = wc * 64 + nt * 16 + ln;
          if (KSPLIT > 1)
            atomicAdd(&out[(size_t)(m0 + row) * E_ + e], acc[mt][nt][r]);
          else
            out[(size_t)(m0 + row) * E_ + e] = acc[mt][nt][r];
        }
  }
}

// ---------------- flash attention (no online rescale) ----------------
// R12 = R11 with the K-staging tile stride fixed: kt*16384 u16 ELEMENTS
// (128 rows x 128 elems), not kt*32768 (that was the byte count -- R11 read
// rows kt*256.., skipping half the keys and crossing into the next head).
// KVBLK=128 within the SAME 2-barrier template: 8 iterations instead of 16
// -> HALF the barrier+vmcnt(0) drain pairs, same staged bytes and MFMA
// count. Key->slot permutation for the 128-wide PV A-operand is bit-identical
// to the vT permutation in global memory (bits{0,1} fixed, {2,3}->{3,4},
// {4}->{2}, bits>=5 untouched), so the producer GEMM is unchanged. QK^T in
// two 64-key halves keeps sa at 32 regs. __launch_bounds__(256,2);
// LDS 65,536 B x 2 blocks/CU = same achieved occupancy as before.
// SWAPPED QK^T (R4): each lane holds P for its own q-row; exp2'd registers
// pack directly into the PV A-operand -> P never touches LDS.
struct SmemKV {
  u16 ks[128 * 128];  // K tile [key][e], chunk-swizzled c = (c'&8)|((c'&7)^(row&7))
  u16 vs[128 * 128];  // V^T tile [e][key-slot], same swizzle (16 chunks/row)
};
union SmemAttn {
  u16 qs[128 * 132];  // Q tile [128][128] pad->132 (init only)
  SmemKV s;           // 65,536 B = union size
};

__global__ __launch_bounds__(256, 2) void attn_kernel(const u16* __restrict__ qg,
                                                      const u16* __restrict__ kg,
                                                      const u16* __restrict__ vg,
                                                      u16* __restrict__ og) {
  __shared__ __align__(16) SmemAttn sm;
  const int tid = threadIdx.x;
  // id = g*64 + qt*8 + x ; hb = g*8 + x ; all qt of one hb share id%8 (XCD)
  const int id = blockIdx.x;
  const int g = id >> 6, qt = (id >> 3) & 7, x = id & 7;
  const int hb = g * 8 + x;
  const int b = hb >> 4, h = hb & 15;
  const int q0 = qt * 128;
  const size_t bh = (size_t)(b * H_ + h);
  const u16* qp = qg + bh * S_ * E_;
  const u16* kp = kg + bh * S_ * E_;
  const u16* vp = vg + bh * E_ * S_;  // [e][key-slot]
  const int w = tid >> 6, lane = tid & 63, quad = lane >> 4, ln = lane & 15;

  // stage Q tile, pull this wave's A-fragments into registers
#pragma unroll
  for (int i = 0; i < 8; i++) {
    int idx = tid + i * 256;
    int row = idx >> 4, col = (idx & 15) * 8;
    *reinterpret_cast<short8*>(&sm.qs[row * 132 + col]) =
        *reinterpret_cast<const short8*>(&qp[(size_t)(q0 + row) * E_ + col]);
  }
  __syncthreads();
  half8 qf[2][4];
#pragma unroll
  for (int mt = 0; mt < 2; mt++)
#pragma unroll
    for (int ks = 0; ks < 4; ks++)
      qf[mt][ks] = *reinterpret_cast<const half8*>(
          &sm.qs[(w * 32 + mt * 16 + ln) * 132 + ks * 32 + quad * 8]);

  // K/V staging (both [128 rows][128 elems], 16 chunks/row): issue i covers
  // rows i*16..i*16+15; chunk L = i*256 + tid; row = i*16 + (tid>>4)
  // (row&7 = (tid>>4)&7, i-invariant); c' = tid&15;
  // global chunk col = (c'&8) | ((c'&7) ^ (row&7)).
  const int srow16 = tid >> 4;
  const int sc16 = tid & 15;
  const int scc16 = (sc16 & 8) | ((sc16 & 7) ^ (srow16 & 7));
  const u16* kbase = kp + (size_t)srow16 * E_ + scc16 * 8;  // + kt*16384 + i*16*E_
  const u16* vbase = vp + (size_t)srow16 * S_ + scc16 * 8;  // + kt*128   + i*16*S_

  f32x4 zero = {0.f, 0.f, 0.f, 0.f};
  f32x4 oa[2][8];
#pragma unroll
  for (int mt = 0; mt < 2; mt++)
#pragma unroll
    for (int nt = 0; nt < 8; nt++) oa[mt][nt] = zero;
  float lsum[2] = {0.f, 0.f};

  for (int kt = 0; kt < 8; kt++) {
    __syncthreads();  // previous compute done with ks/vs (and init: qs reads)
#pragma unroll
    for (int i = 0; i < 8; i++) {
      gl2lds16(kbase + (size_t)kt * 16384 + i * 16 * E_, &sm.s.ks[(i * 256 + w * 64) * 8]);
      gl2lds16(vbase + (size_t)kt * 128   + i * 16 * S_, &sm.s.vs[(i * 256 + w * 64) * 8]);
    }
    __syncthreads();  // vmcnt drain -> tiles visible

    // S^T = K Q^T in two 64-key halves (keeps sa at 32 regs).
    // Lane (ln,quad) holds P[qrow=ln][key = half*64 + nt*16 + quad*4 + r];
    // key -> PV-slot permutation matches vT's global layout.
    half8 pfr[2][4];
#pragma unroll
    for (int half = 0; half < 2; half++) {
      f32x4 sa[2][4];
#pragma unroll
      for (int mt = 0; mt < 2; mt++)
#pragma unroll
        for (int nt = 0; nt < 4; nt++) sa[mt][nt] = zero;
#pragma unroll
      for (int ks = 0; ks < 4; ks++) {
        half8 kf[4];
#pragma unroll
        for (int nt = 0; nt < 4; nt++) {
          int c = ks * 4 + quad;
          int cs = (c & 8) | ((c & 7) ^ (ln & 7));
          kf[nt] = *reinterpret_cast<const half8*>(
              &sm.s.ks[((half * 64) + nt * 16 + ln) * 128 + cs * 8]);
        }
#pragma unroll
        for (int mt = 0; mt < 2; mt++)
#pragma unroll
          for (int nt = 0; nt < 4; nt++)
            sa[mt][nt] = __builtin_amdgcn_mfma_f32_16x16x32_f16(kf[nt], qf[mt][ks], sa[mt][nt], 0, 0, 0);
      }
      // pack p = exp2(s) straight into PV A-operand halves half*2 .. half*2+1
#pragma unroll
      for (int mt = 0; mt < 2; mt++) {
        float psum = 0.f;
#pragma unroll
        for (int h2 = 0; h2 < 2; h2++) {
          half8 ph;
#pragma unroll
          for (int hh = 0; hh < 2; hh++)
#pragma unroll
            for (int r = 0; r < 4; r++) {
              float p = exp2f(sa[mt][h2 * 2 + hh][r]);
              psum += p;
              ph[hh * 4 + r] = (f16)p;
            }
          pfr[mt][half * 2 + h2] = ph;
        }
        lsum[mt] += psum;
      }
    }

    // O += P V (P from registers; no LDS, no barrier). 4 k-steps of 32 slots.
#pragma unroll
    for (int k2 = 0; k2 < 4; k2++) {
#pragma unroll
      for (int nt8 = 0; nt8 < 8; nt8++) {
        int c = k2 * 4 + quad;
        int cs = (c & 8) | ((c & 7) ^ (ln & 7));
        half8 vf = *reinterpret_cast<const half8*>(&sm.s.vs[(nt8 * 16 + ln) * 128 + cs * 8]);
#pragma unroll
        for (int mt = 0; mt < 2; mt++)
          oa[mt][nt8] = __builtin_amdgcn_mfma_f32_16x16x32_f16(pfr[mt][k2], vf, oa[mt][nt8], 0, 0, 0);
      }
    }
  }

  // epilogue: row-sum lives per-lane for qrow=ln; reduce across quads,
  // fetch the right row's sum via shfl, normalize, store.
#pragma unroll
  for (int mt = 0; mt < 2; mt++) {
    float l = lsum[mt];
    l += __shfl_xor(l, 16);
    l += __shfl_xor(l, 32);   // every lane: row-sum for qrow = w*32+mt*16+ln
#pragma unroll
    for (int r = 0; r < 4; r++) {
      float lr = __shfl(l, quad * 4 + r);  // lane (quad*4+r) has ln=quad*4+r
      float rl = 1.0f / lr;
      int srow = q0 + w * 32 + mt * 16 + quad * 4 + r;  // C/D row = quad*4+reg
      size_t base = ((size_t)b * S_ + srow) * (H_ * E_) + (size_t)h * E_;
#pragma unroll
      for (int nt8 = 0; nt8 < 8; nt8++)
        og[base + nt8 * 16 + ln] = f2h(oa[mt][nt8][r] * rl);
    }
  }
}

// ---------------- launch ----------------
extern "C" void kernel_launch(void* const* d_in, const int* in_sizes, int n_in,
                              void* d_out, int out_size, void* d_ws, size_t ws_size,
                              hipStream_t stream) {
  const float* x = (const float*)d_in[0];    // [16,1024,1024]
  const float* W = (const float*)d_in[1];    // [16,3,1024,128]
  const float* Wo = (const float*)d_in[2];   // [2048,128]
  float* out = (float*)d_out;                // [16,1024,128] fp32
  char* ws = (char*)d_ws;

  const size_t WBT_BYTES = (size_t)H_ * 3 * DIN_ * E_ * 2;   // 12,582,912
  const size_t WOT_BYTES = (size_t)H_ * E_ * E_ * 2 * 2;     //    524,288
  const size_t FIXED = WBT_BYTES + WOT_BYTES;

  const size_t XB_PER   = (size_t)S_ * DIN_ * 2;
  const size_t QKV_PER  = (size_t)H_ * S_ * E_ * 2;
  const size_t OB_PER   = (size_t)S_ * H_ * E_ * 2;
  const size_t PER_ITEM = XB_PER + 3 * QKV_PER + OB_PER;     // 18,874,368

  int Bc = 1;
  for (int c = 16; c >= 1; c >>= 1) {
    if (FIXED + (size_t)c * PER_ITEM <= ws_size) { Bc = c; break; }
  }

  u16* WbT = (u16*)(ws);
  u16* WoT = (u16*)(ws + WBT_BYTES);
  char* cb = ws + FIXED;
  u16* xb  = (u16*)(cb);
  u16* qb  = (u16*)(cb + (size_t)Bc * XB_PER);
  u16* kb  = (u16*)(cb + (size_t)Bc * (XB_PER + QKV_PER));
  u16* vTb = (u16*)(cb + (size_t)Bc * (XB_PER + 2 * QKV_PER));
  u16* ob  = (u16*)(cb + (size_t)Bc * (XB_PER + 3 * QKV_PER));

  zero_f32<<<out_size / 1024, 256, 0, stream>>>(out);  // split-K outproj accumulates
  transpose_cvt<<<dim3(4, 32, 48), 256, 0, stream>>>(W, WbT, DIN_, E_);
  transpose_cvt<<<dim3(4, 64, 1), 256, 0, stream>>>(Wo, WoT, H_ * E_, E_);

  for (int b0 = 0; b0 < B_; b0 += Bc) {
    const float* xc = x + (size_t)b0 * S_ * DIN_;
    cvt_f32_f16<<<Bc * S_ * DIN_ / 1024, 256, 0, stream>>>(xc, xb);
    gemm256_qkv<DIN_><<<dim3(Bc * 4, 24), 512, 0, stream>>>(xb, WbT, qb, kb, vTb);
    attn_kernel<<<Bc * 128, 256, 0, stream>>>(qb, kb, vTb, ob);
    gemm_bt<1, 4, H_ * E_><<<dim3(Bc * 8, 1, 4), 256, 0, stream>>>(ob, WoT, nullptr, nullptr,
                                                                   nullptr, out + (size_t)b0 * S_ * E_);
  }
}